// Round 11
// baseline (319.690 us; speedup 1.0000x reference)
//
#include <hip/hip_runtime.h>
#include <math.h>

#define NN   10000
#define EE   200000
#define RR   400000
#define FIN  128
#define FOUT 64

#define HASH_BITS 20
#define HSIZE (1u << HASH_BITS)
#define HMASK (HSIZE - 1u)
#define ROWCAP 256           // per-row edge slots (Poisson(40): P(>256)~0)

#define NKB 314              // k-blocks of 32 covering 10048

typedef __bf16 bf16x8 __attribute__((ext_vector_type(8)));
typedef __bf16 bf16x4 __attribute__((ext_vector_type(4)));
typedef float  f32x4  __attribute__((ext_vector_type(4)));

// ---- workspace layout (units of 4 bytes) ----
#define O_SUMS   0
#define O_CNTS   (O_SUMS + EE)
#define O_ROWCNT (O_CNTS + EE)             // int[NN]
#define O_HKEY   (O_ROWCNT + NN)
#define O_HPRIO  (O_HKEY + HSIZE)
#define O_SEQTP  (O_HPRIO + HSIZE)         // packed bf16 [NKB][5][64][8]
#define SEQTP_WORDS (NKB * 5 * 512 / 2)
#define ZERO_WORDS (O_SEQTP + SEQTP_WORDS) // div by 4
#define O_NUMP   ZERO_WORDS                // f32[8][NN][64]
#define O_SP     (O_NUMP + 8 * NN * FOUT)  // f32[8][NN]
#define O_PAIRS  (O_SP + 8 * NN)           // uint2[NN][ROWCAP]

// ---------------- wide zero fill ----------------
__global__ __launch_bounds__(256) void k_zero(f32x4* __restrict__ p, int n4) {
    int gid = blockIdx.x * 256 + threadIdx.x;
    if (gid < n4) p[gid] = (f32x4){0.f, 0.f, 0.f, 0.f};
}

// -------- seq_fts = x @ W^T, emitted as MFMA-fragment-packed bf16 ----------
// packed(kb, n, lane, slot) = seq[col = n*16+(lane&15)][k = kb*32+(lane>>4)*8+slot]
// n==4 is the all-ones fragment (row-sum via MFMA).
__global__ __launch_bounds__(256) void k_seqfts(const float* __restrict__ x,
                                                const float* __restrict__ W,
                                                __bf16* __restrict__ seqTp) {
    __shared__ float Wt[FIN][FOUT + 1];
    __shared__ float xs[FIN][16 + 1];
    int t = threadIdx.x;
    for (int e = t; e < FOUT * FIN; e += 256) {
        int c = e >> 7, k = e & 127;
        Wt[k][c] = W[e];
    }
    int row0 = blockIdx.x * 16;
    for (int e = t; e < 16 * FIN; e += 256) {
        int r = e >> 7, k = e & 127;
        int gr = row0 + r;
        xs[k][r] = (gr < NN) ? x[(size_t)gr * FIN + k] : 0.f;
    }
    __syncthreads();
    int col = t & 63;
    int rg  = t >> 6;
    float acc[4] = {0.f, 0.f, 0.f, 0.f};
    for (int k = 0; k < FIN; ++k) {
        float w = Wt[k][col];
        #pragma unroll
        for (int i = 0; i < 4; ++i) acc[i] += w * xs[k][rg * 4 + i];
    }
    #pragma unroll
    for (int i = 0; i < 4; ++i) {
        int gr = row0 + rg * 4 + i;          // gr = K index, always < NN here
        int kb = gr >> 5, g = (gr >> 3) & 3, slot = gr & 7;
        seqTp[((size_t)kb * 5 + (col >> 4)) * 512 + ((col & 15) + g * 16) * 8 + slot]
            = (__bf16)acc[i];
        if (col < 16)
            seqTp[((size_t)kb * 5 + 4) * 512 + (col + g * 16) * 8 + slot] = (__bf16)1.0f;
    }
}

// ---------------- helpers ----------------
__device__ __forceinline__ unsigned hash_cell(unsigned cell) {
    return (cell * 2654435761u) >> (32 - HASH_BITS);
}
__device__ __forceinline__ void entry_ij(const int* ep, int e, int& i, int& j, int& k) {
    k = (e < EE) ? e : e - EE;
    int a = ep[2 * k], b = ep[2 * k + 1];
    if (e < EE) { i = a; j = b; } else { i = b; j = a; }
}

// ------- merged: main matmul (B from L2 regs) || rel segsum || hash --------
#define BM 64
#define BK 64
#define KSPLIT 8
#define NCHUNK 157
#define CPK 20
#define MAINB (NCHUNK * KSPLIT)                // 1256
#define ILV   11                               // 1 main : 10 rel
#define MRB   (ILV * MAINB)                    // 13816 (12560 rel slots)
#define SCATAB ((2 * EE + 255) / 256)          // 1563
#define GRID_MR (MRB + SCATAB)
#define LDAP 72                                // bf16 row stride (144B, 16B-aligned)

__global__ __launch_bounds__(256) void k_mainrel(const float* __restrict__ adj,
                                                 const __bf16* __restrict__ seqTp,
                                                 const float* __restrict__ rel,
                                                 const float* __restrict__ wrel,
                                                 const int* __restrict__ rseg,
                                                 const int* __restrict__ ep,
                                                 float* __restrict__ sums,
                                                 float* __restrict__ cnts,
                                                 unsigned* __restrict__ hkey,
                                                 unsigned* __restrict__ hprio,
                                                 float* __restrict__ Nump,
                                                 float* __restrict__ Sp) {
    __shared__ __bf16 As[2][BM][LDAP];      // 18432 B (half of old 36864)
    int t   = threadIdx.x;
    int bid = blockIdx.x;

    if (bid >= MRB) {
        // ---- hash-build role ----
        int e = (bid - MRB) * 256 + t;
        if (e >= 2 * EE) return;
        int i, j, k;
        entry_ij(ep, e, i, j, k);
        unsigned cell = (unsigned)i * NN + (unsigned)j;
        unsigned keyv = cell + 1u;
        unsigned h = hash_cell(cell);
        while (true) {
            unsigned old = atomicCAS(&hkey[h], 0u, keyv);
            if (old == 0u || old == keyv) break;
            h = (h + 1u) & HMASK;
        }
        atomicMax(&hprio[h], (unsigned)(e + 1));
        return;
    }

    if (bid % ILV) {
        // ---- rel role: 32 rows per block, 32-lane group per row ----
        int relb = bid - bid / ILV - 1;        // [0, 12560)
        int lane = t & 31;
        f32x4 w = *(const f32x4*)(wrel + lane * 4);
        #pragma unroll
        for (int it = 0; it < 4; ++it) {
            int row = relb * 32 + it * 8 + (t >> 5);
            if (row < RR) {
                f32x4 v = *(const f32x4*)(rel + (size_t)row * FIN + lane * 4);
                float s = v.x * w.x + v.y * w.y + v.z * w.z + v.w * w.w;
                #pragma unroll
                for (int off = 16; off >= 1; off >>= 1) s += __shfl_xor(s, off, 64);
                if (lane == 0) {
                    int seg = rseg[row];
                    atomicAdd(&sums[seg], s);
                    atomicAdd(&cnts[seg], 1.0f);
                }
            }
        }
        return;
    }

    // ---- main role: 64x64 tile, A staged in LDS (dbuf, 1 barrier/chunk),
    //      B-fragments straight from L2-resident packed seqTp into regs. ----
    int mi   = bid / ILV;
    int rowc = mi % NCHUNK;
    int ks   = mi / NCHUNK;
    int row0 = rowc * BM;
    int c0   = ks * CPK;
    int c1   = min(NCHUNK, c0 + CPK);
    int w  = t >> 6, l = t & 63;
    int lr = l & 15, lk = l >> 4;
    int sr = t >> 4;               // A-stage row within 16-row strip
    int sk = (t & 15) * 4;         // A-stage col (f32x4)

    f32x4 acc[5];
    #pragma unroll
    for (int n = 0; n < 5; ++n) acc[n] = (f32x4){0.f, 0.f, 0.f, 0.f};

    f32x4 pvA[4], pvB[4];

#define LOADA(PV, CH)                                                          \
    {                                                                          \
        int k0_ = (CH) * BK;                                                   \
        _Pragma("unroll")                                                      \
        for (int e2 = 0; e2 < 4; ++e2) {                                       \
            int gr = row0 + sr + e2 * 16;                                      \
            int gk = k0_ + sk;                                                 \
            PV[e2] = (gr < NN && gk < NN)                                      \
                         ? *(const f32x4*)(adj + (size_t)gr * NN + gk)         \
                         : (f32x4){-1e9f, -1e9f, -1e9f, -1e9f};                \
        }                                                                      \
    }

#define BODY(PV, CH, P_)                                                       \
    {                                                                          \
        _Pragma("unroll")                                                      \
        for (int e2 = 0; e2 < 4; ++e2) {                                       \
            f32x4 v = PV[e2];                                                  \
            float e0 = exp2f(fmaf(v.x, 1.442695041f, 0.7213475204f));          \
            float e1 = exp2f(fmaf(v.y, 1.442695041f, 0.7213475204f));          \
            float e2f = exp2f(fmaf(v.z, 1.442695041f, 0.7213475204f));         \
            float e3 = exp2f(fmaf(v.w, 1.442695041f, 0.7213475204f));          \
            bf16x4 q = { (__bf16)e0, (__bf16)e1, (__bf16)e2f, (__bf16)e3 };    \
            *(bf16x4*)&As[P_][sr + e2 * 16][sk] = q;                           \
        }                                                                      \
        const __bf16* bp = seqTp + (size_t)(CH) * 2 * 5 * 512 + l * 8;         \
        bf16x8 b0 = *(const bf16x8*)(bp);                                      \
        bf16x8 b1 = *(const bf16x8*)(bp + 512);                                \
        bf16x8 b2 = *(const bf16x8*)(bp + 1024);                               \
        bf16x8 b3 = *(const bf16x8*)(bp + 1536);                               \
        bf16x8 b4 = *(const bf16x8*)(bp + 2048);                               \
        __syncthreads();                                                       \
        bf16x8 a0 = *(const bf16x8*)&As[P_][w * 16 + lr][lk * 8];              \
        acc[0] = __builtin_amdgcn_mfma_f32_16x16x32_bf16(a0, b0, acc[0], 0, 0, 0); \
        acc[1] = __builtin_amdgcn_mfma_f32_16x16x32_bf16(a0, b1, acc[1], 0, 0, 0); \
        acc[2] = __builtin_amdgcn_mfma_f32_16x16x32_bf16(a0, b2, acc[2], 0, 0, 0); \
        acc[3] = __builtin_amdgcn_mfma_f32_16x16x32_bf16(a0, b3, acc[3], 0, 0, 0); \
        acc[4] = __builtin_amdgcn_mfma_f32_16x16x32_bf16(a0, b4, acc[4], 0, 0, 0); \
        const __bf16* bq = bp + 2560;                                          \
        bf16x8 d0 = *(const bf16x8*)(bq);                                      \
        bf16x8 d1 = *(const bf16x8*)(bq + 512);                                \
        bf16x8 d2 = *(const bf16x8*)(bq + 1024);                               \
        bf16x8 d3 = *(const bf16x8*)(bq + 1536);                               \
        bf16x8 d4 = *(const bf16x8*)(bq + 2048);                               \
        bf16x8 a1 = *(const bf16x8*)&As[P_][w * 16 + lr][32 + lk * 8];         \
        acc[0] = __builtin_amdgcn_mfma_f32_16x16x32_bf16(a1, d0, acc[0], 0, 0, 0); \
        acc[1] = __builtin_amdgcn_mfma_f32_16x16x32_bf16(a1, d1, acc[1], 0, 0, 0); \
        acc[2] = __builtin_amdgcn_mfma_f32_16x16x32_bf16(a1, d2, acc[2], 0, 0, 0); \
        acc[3] = __builtin_amdgcn_mfma_f32_16x16x32_bf16(a1, d3, acc[3], 0, 0, 0); \
        acc[4] = __builtin_amdgcn_mfma_f32_16x16x32_bf16(a1, d4, acc[4], 0, 0, 0); \
    }

    LOADA(pvA, c0);
    int ch = c0, p = 0;
    while (true) {
        if (ch + 1 < c1) LOADA(pvB, ch + 1);   // prefetch flies over stage VALU
        BODY(pvA, ch, p);
        p ^= 1; ++ch;
        if (ch >= c1) break;
        if (ch + 1 < c1) LOADA(pvA, ch + 1);
        BODY(pvB, ch, p);
        p ^= 1; ++ch;
        if (ch >= c1) break;
    }
#undef LOADA
#undef BODY

    // C/D layout: col = lane&15, row = (lane>>4)*4 + reg
    float* nout = Nump + (size_t)ks * NN * FOUT;
    #pragma unroll
    for (int n = 0; n < 4; ++n) {
        #pragma unroll
        for (int r = 0; r < 4; ++r) {
            int grow = row0 + w * 16 + lk * 4 + r;
            if (grow < NN)
                nout[(size_t)grow * FOUT + n * 16 + lr] = acc[n][r];
        }
    }
    if (lr == 0) {                      // ones-fragment -> f32 row sums
        #pragma unroll
        for (int r = 0; r < 4; ++r) {
            int grow = row0 + w * 16 + lk * 4 + r;
            if (grow < NN) Sp[(size_t)ks * NN + grow] = acc[4][r];
        }
    }
}

// ------- scatB: winner check + dw compute + push (j,dw) into row bucket -----
__global__ __launch_bounds__(256) void k_scatB(const int* __restrict__ ep,
                                               const float* __restrict__ sums,
                                               const float* __restrict__ cnts,
                                               const unsigned* __restrict__ hkey,
                                               const unsigned* __restrict__ hprio,
                                               const float* __restrict__ adj,
                                               int* __restrict__ rowcnt,
                                               uint2* __restrict__ pairs) {
    int e = blockIdx.x * 256 + threadIdx.x;
    if (e >= 2 * EE) return;
    int i, j, k;
    entry_ij(ep, e, i, j, k);
    unsigned cell = (unsigned)i * NN + (unsigned)j;
    unsigned keyv = cell + 1u;
    unsigned h = hash_cell(cell);
    while (hkey[h] != keyv) h = (h + 1u) & HMASK;
    if (hprio[h] == (unsigned)(e + 1)) {   // last-write-wins winner
        float v   = sums[k] / fmaxf(cnts[k], 1.0f);
        float sg  = 1.f / (1.f + __expf(-v));
        float aij = adj[(size_t)i * NN + j];
        float dw  = __expf(aij + sg) - __expf(aij + 0.5f);
        if (dw != 0.f) {
            int pos = atomicAdd(&rowcnt[i], 1);
            if (pos < ROWCAP)
                pairs[(size_t)i * ROWCAP + pos] =
                    make_uint2((unsigned)j, __float_as_uint(dw));
        }
    }
}

// ------- rowupd: one wave per row: sum partials + edge corr + elu -> out ----
__global__ __launch_bounds__(256) void k_rowupd(const float* __restrict__ Nump,
                                                const float* __restrict__ Sp,
                                                const int* __restrict__ rowcnt,
                                                const uint2* __restrict__ pairs,
                                                const __bf16* __restrict__ seqTp,
                                                const float* __restrict__ bias,
                                                float* __restrict__ out) {
    int t = threadIdx.x;
    int i = blockIdx.x * 4 + (t >> 6);
    if (i >= NN) return;
    int c = t & 63;
    float acc = 0.f, sb = 0.f;
    #pragma unroll
    for (int ks = 0; ks < 8; ++ks) {
        acc += Nump[(size_t)ks * NN * FOUT + (size_t)i * FOUT + c];
        sb  += Sp[(size_t)ks * NN + i];
    }
    int cnt = min(rowcnt[i], ROWCAP);
    float sdw = 0.f;
    const uint2* pr = pairs + (size_t)i * ROWCAP;
    for (int e = 0; e < cnt; ++e) {
        uint2 pk = pr[e];                      // wave-uniform broadcast load
        float d  = __uint_as_float(pk.y);
        unsigned j = pk.x;
        float sj = (float)seqTp[((size_t)(j >> 5) * 5 + (c >> 4)) * 512
                                + ((c & 15) + ((j >> 3) & 3) * 16) * 8 + (j & 7)];
        acc += d * sj;
        sdw += d;
    }
    float v = acc / (sb + sdw) + bias[c];
    out[(size_t)i * FOUT + c] = (v > 0.f) ? v : expm1f(v);
}

extern "C" void kernel_launch(void* const* d_in, const int* in_sizes, int n_in,
                              void* d_out, int out_size, void* d_ws, size_t ws_size,
                              hipStream_t stream) {
    const float* x    = (const float*)d_in[0];
    const float* rel  = (const float*)d_in[1];
    const float* adj  = (const float*)d_in[2];
    const int*   ep   = (const int*)d_in[3];
    const int*   rseg = (const int*)d_in[4];
    const float* W    = (const float*)d_in[5];
    const float* wrel = (const float*)d_in[6];
    const float* bias = (const float*)d_in[7];
    float* out = (float*)d_out;

    float* ws = (float*)d_ws;
    float*    sums   = ws + O_SUMS;
    float*    cnts   = ws + O_CNTS;
    int*      rowcnt = (int*)(ws + O_ROWCNT);
    unsigned* hkey   = (unsigned*)(ws + O_HKEY);
    unsigned* hprio  = (unsigned*)(ws + O_HPRIO);
    __bf16*   seqTp  = (__bf16*)(ws + O_SEQTP);
    float*    Nump   = ws + O_NUMP;
    float*    Sp     = ws + O_SP;
    uint2*    pairs  = (uint2*)(ws + O_PAIRS);

    int n4 = ZERO_WORDS / 4;
    k_zero<<<(n4 + 255) / 256, 256, 0, stream>>>((f32x4*)d_ws, n4);
    k_seqfts<<<NN / 16, 256, 0, stream>>>(x, W, seqTp);
    k_mainrel<<<GRID_MR, 256, 0, stream>>>(adj, seqTp, rel, wrel, rseg, ep,
                                           sums, cnts, hkey, hprio, Nump, Sp);
    k_scatB<<<(2 * EE + 255) / 256, 256, 0, stream>>>(ep, sums, cnts, hkey, hprio,
                                                      adj, rowcnt, pairs);
    k_rowupd<<<(NN + 3) / 4, 256, 0, stream>>>(Nump, Sp, rowcnt, pairs,
                                               seqTp, bias, out);
}

// Round 12
// 318.781 us; speedup vs baseline: 1.0029x; 1.0029x over previous
//
#include <hip/hip_runtime.h>
#include <math.h>

#define NN   10000
#define EE   200000
#define RR   400000
#define FIN  128
#define FOUT 64

#define HASH_BITS 20
#define HSIZE (1u << HASH_BITS)
#define HMASK (HSIZE - 1u)
#define ROWCAP 256           // per-row edge slots (Poisson(40): P(>256)~0)

#define NKB 314              // k-blocks of 32 covering 10048

typedef __bf16 bf16x8 __attribute__((ext_vector_type(8)));
typedef __bf16 bf16x4 __attribute__((ext_vector_type(4)));
typedef float  f32x4  __attribute__((ext_vector_type(4)));

// ---- workspace layout (units of 4 bytes) ----
#define O_SUMS   0
#define O_CNTS   (O_SUMS + EE)
#define O_ROWCNT (O_CNTS + EE)             // int[NN]
#define O_HKEY   (O_ROWCNT + NN)
#define O_HPRIO  (O_HKEY + HSIZE)
#define O_SEQTP  (O_HPRIO + HSIZE)         // packed bf16 [NKB][5][64][8]
#define SEQTP_WORDS (NKB * 5 * 512 / 2)
#define ZERO_WORDS (O_SEQTP + SEQTP_WORDS) // div by 4
#define O_NUMP   ZERO_WORDS                // f32[8][NN][64] partials
#define O_SP     (O_NUMP + 8 * NN * FOUT)  // f32[8][NN]
#define O_PAIRS  (O_SP + 8 * NN)           // uint2[NN][ROWCAP]

// ---------------- wide zero fill ----------------
__global__ __launch_bounds__(256) void k_zero(f32x4* __restrict__ p, int n4) {
    int gid = blockIdx.x * 256 + threadIdx.x;
    if (gid < n4) p[gid] = (f32x4){0.f, 0.f, 0.f, 0.f};
}

// -------- seq_fts = x @ W^T, emitted as MFMA-fragment-packed bf16 ----------
// packed(kb, n, lane, slot) = seq[col = n*16+(lane&15)][k = kb*32+(lane>>4)*8+slot]
// n==4 is the all-ones fragment (row-sum via MFMA).
__global__ __launch_bounds__(256) void k_seqfts(const float* __restrict__ x,
                                                const float* __restrict__ W,
                                                __bf16* __restrict__ seqTp) {
    __shared__ float Wt[FIN][FOUT + 1];
    __shared__ float xs[FIN][16 + 1];
    int t = threadIdx.x;
    for (int e = t; e < FOUT * FIN; e += 256) {
        int c = e >> 7, k = e & 127;
        Wt[k][c] = W[e];
    }
    int row0 = blockIdx.x * 16;
    for (int e = t; e < 16 * FIN; e += 256) {
        int r = e >> 7, k = e & 127;
        int gr = row0 + r;
        xs[k][r] = (gr < NN) ? x[(size_t)gr * FIN + k] : 0.f;
    }
    __syncthreads();
    int col = t & 63;
    int rg  = t >> 6;
    float acc[4] = {0.f, 0.f, 0.f, 0.f};
    for (int k = 0; k < FIN; ++k) {
        float w = Wt[k][col];
        #pragma unroll
        for (int i = 0; i < 4; ++i) acc[i] += w * xs[k][rg * 4 + i];
    }
    #pragma unroll
    for (int i = 0; i < 4; ++i) {
        int gr = row0 + rg * 4 + i;          // gr = K index, always < NN here
        int kb = gr >> 5, g = (gr >> 3) & 3, slot = gr & 7;
        seqTp[((size_t)kb * 5 + (col >> 4)) * 512 + ((col & 15) + g * 16) * 8 + slot]
            = (__bf16)acc[i];
        if (col < 16)
            seqTp[((size_t)kb * 5 + 4) * 512 + (col + g * 16) * 8 + slot] = (__bf16)1.0f;
    }
}

// ---------------- helpers ----------------
__device__ __forceinline__ unsigned hash_cell(unsigned cell) {
    return (cell * 2654435761u) >> (32 - HASH_BITS);
}
__device__ __forceinline__ void entry_ij(const int* ep, int e, int& i, int& j, int& k) {
    k = (e < EE) ? e : e - EE;
    int a = ep[2 * k], b = ep[2 * k + 1];
    if (e < EE) { i = a; j = b; } else { i = b; j = a; }
}

// ------- fused: page-optimal main matmul || rel segsum || hash build -------
// main: 625 blocks x 16 rows, 512 thr (8 waves). Each row consumed in full
// 2KB-page steps (4 back-to-back 512B loads per page per wave). K-chunk=512,
// K-split across the 8 waves for MFMA; B-frags from L2-resident packed seqTp;
// row sums via the ones fragment. 1-barrier double-buffered LDS.
#define NC 20
#define CHKF 512
#define LDSP 520
#define MAINBLK 625                        // NN/16
#define ILV 11                             // 1 main : 10 rel
#define MRB (ILV * MAINBLK)                // 6875 (6250 rel slots, exact)
#define HASHB ((2 * EE + 511) / 512)       // 782
#define GRID_MR (MRB + HASHB)

__global__ __launch_bounds__(512) void k_mr(const float* __restrict__ adj,
                                            const __bf16* __restrict__ seqTp,
                                            const float* __restrict__ rel,
                                            const float* __restrict__ wrel,
                                            const int* __restrict__ rseg,
                                            const int* __restrict__ ep,
                                            float* __restrict__ sums,
                                            float* __restrict__ cnts,
                                            unsigned* __restrict__ hkey,
                                            unsigned* __restrict__ hprio,
                                            float* __restrict__ Nump,
                                            float* __restrict__ Sp) {
    __shared__ __bf16 As[2][16][LDSP];     // 33,280 B
    int t   = threadIdx.x;
    int bid = blockIdx.x;

    if (bid >= MRB) {
        // ---- hash-build role ----
        int e = (bid - MRB) * 512 + t;
        if (e >= 2 * EE) return;
        int i, j, k;
        entry_ij(ep, e, i, j, k);
        unsigned cell = (unsigned)i * NN + (unsigned)j;
        unsigned keyv = cell + 1u;
        unsigned h = hash_cell(cell);
        while (true) {
            unsigned old = atomicCAS(&hkey[h], 0u, keyv);
            if (old == 0u || old == keyv) break;
            h = (h + 1u) & HMASK;
        }
        atomicMax(&hprio[h], (unsigned)(e + 1));
        return;
    }

    if (bid % ILV) {
        // ---- rel role: 64 rows per block, 32-lane group per row ----
        int relb = bid - bid / ILV - 1;    // [0, 6250), exact coverage
        int lane = t & 31;
        f32x4 wv = *(const f32x4*)(wrel + lane * 4);
        int rbase = relb * 64 + (t >> 5);  // 16 rows per pass
        #pragma unroll
        for (int pass = 0; pass < 4; ++pass) {
            int row = rbase + pass * 16;   // < RR always (6250*64 == RR)
            f32x4 v = *(const f32x4*)(rel + (size_t)row * FIN + lane * 4);
            float s = v.x * wv.x + v.y * wv.y + v.z * wv.z + v.w * wv.w;
            #pragma unroll
            for (int off = 16; off >= 1; off >>= 1) s += __shfl_xor(s, off, 64);
            if (lane == 0) {
                int seg = rseg[row];
                atomicAdd(&sums[seg], s);
                atomicAdd(&cnts[seg], 1.0f);
            }
        }
        return;
    }

    // ---- main role ----
    int mi   = bid / ILV;                  // [0, 625)
    int row0 = mi * 16;
    int w  = t >> 6, l = t & 63;
    int lr = l & 15, lk = l >> 4;
    int sr = t >> 5;                       // staging row 0..15
    int sq = t & 31;                       // staging quad within row
    const float* arow = adj + (size_t)(row0 + sr) * NN;

    f32x4 acc[5];
    #pragma unroll
    for (int n = 0; n < 5; ++n) acc[n] = (f32x4){0.f, 0.f, 0.f, 0.f};

    f32x4 pv[4];
#define LOADW(CH)                                                          \
    {                                                                      \
        int kbase = (CH) * CHKF + sq * 4;                                  \
        _Pragma("unroll")                                                  \
        for (int s = 0; s < 4; ++s) {                                      \
            int gk = kbase + s * 128;                                      \
            pv[s] = (gk < NN) ? *(const f32x4*)(arow + gk)                 \
                              : (f32x4){-1e9f, -1e9f, -1e9f, -1e9f};      \
        }                                                                  \
    }

    LOADW(0);
    int p = 0;
    for (int c = 0; c < NC; ++c) {
        // stage: exp + bf16 pack -> As[p]
        #pragma unroll
        for (int s = 0; s < 4; ++s) {
            f32x4 v = pv[s];
            float e0 = exp2f(fmaf(v.x, 1.442695041f, 0.7213475204f));
            float e1 = exp2f(fmaf(v.y, 1.442695041f, 0.7213475204f));
            float e2 = exp2f(fmaf(v.z, 1.442695041f, 0.7213475204f));
            float e3 = exp2f(fmaf(v.w, 1.442695041f, 0.7213475204f));
            bf16x4 q = { (__bf16)e0, (__bf16)e1, (__bf16)e2, (__bf16)e3 };
            *(bf16x4*)&As[p][sr][sq * 4 + s * 128] = q;
        }
        if (c + 1 < NC) LOADW(c + 1);      // prefetch next page-window
        __syncthreads();                    // 1 barrier per chunk (dbuf)
        int kb0 = c * 16;
        #pragma unroll
        for (int h = 0; h < 2; ++h) {
            int kb = kb0 + w * 2 + h;
            if (kb < NKB) {
                bf16x8 af = *(const bf16x8*)&As[p][lr][(w * 2 + h) * 32 + lk * 8];
                const __bf16* bp = seqTp + (size_t)kb * 5 * 512 + l * 8;
                #pragma unroll
                for (int n = 0; n < 5; ++n) {
                    bf16x8 b = *(const bf16x8*)(bp + n * 512);
                    acc[n] = __builtin_amdgcn_mfma_f32_16x16x32_bf16(af, b, acc[n], 0, 0, 0);
                }
            }
        }
        p ^= 1;
    }
#undef LOADW

    // C/D layout: col = lane&15, row = (lane>>4)*4 + reg ; per-wave partial
    float* nout = Nump + (size_t)w * NN * FOUT;
    #pragma unroll
    for (int n = 0; n < 4; ++n) {
        #pragma unroll
        for (int r = 0; r < 4; ++r)
            nout[(size_t)(row0 + lk * 4 + r) * FOUT + n * 16 + lr] = acc[n][r];
    }
    if (lr == 0) {                          // ones-fragment -> f32 row sums
        #pragma unroll
        for (int r = 0; r < 4; ++r)
            Sp[(size_t)w * NN + row0 + lk * 4 + r] = acc[4][r];
    }
}

// ------- scatB: winner check + dw compute + push (j,dw) into row bucket -----
__global__ __launch_bounds__(256) void k_scatB(const int* __restrict__ ep,
                                               const float* __restrict__ sums,
                                               const float* __restrict__ cnts,
                                               const unsigned* __restrict__ hkey,
                                               const unsigned* __restrict__ hprio,
                                               const float* __restrict__ adj,
                                               int* __restrict__ rowcnt,
                                               uint2* __restrict__ pairs) {
    int e = blockIdx.x * 256 + threadIdx.x;
    if (e >= 2 * EE) return;
    int i, j, k;
    entry_ij(ep, e, i, j, k);
    unsigned cell = (unsigned)i * NN + (unsigned)j;
    unsigned keyv = cell + 1u;
    unsigned h = hash_cell(cell);
    while (hkey[h] != keyv) h = (h + 1u) & HMASK;
    if (hprio[h] == (unsigned)(e + 1)) {   // last-write-wins winner
        float v   = sums[k] / fmaxf(cnts[k], 1.0f);
        float sg  = 1.f / (1.f + __expf(-v));
        float aij = adj[(size_t)i * NN + j];
        float dw  = __expf(aij + sg) - __expf(aij + 0.5f);
        if (dw != 0.f) {
            int pos = atomicAdd(&rowcnt[i], 1);
            if (pos < ROWCAP)
                pairs[(size_t)i * ROWCAP + pos] =
                    make_uint2((unsigned)j, __float_as_uint(dw));
        }
    }
}

// ------- rowupd: one wave per row: sum partials + edge corr + elu -> out ----
__global__ __launch_bounds__(256) void k_rowupd(const float* __restrict__ Nump,
                                                const float* __restrict__ Sp,
                                                const int* __restrict__ rowcnt,
                                                const uint2* __restrict__ pairs,
                                                const __bf16* __restrict__ seqTp,
                                                const float* __restrict__ bias,
                                                float* __restrict__ out) {
    int t = threadIdx.x;
    int i = blockIdx.x * 4 + (t >> 6);
    if (i >= NN) return;
    int c = t & 63;
    float acc = 0.f, sb = 0.f;
    #pragma unroll
    for (int ks = 0; ks < 8; ++ks) {
        acc += Nump[(size_t)ks * NN * FOUT + (size_t)i * FOUT + c];
        sb  += Sp[(size_t)ks * NN + i];
    }
    int cnt = min(rowcnt[i], ROWCAP);
    float sdw = 0.f;
    const uint2* pr = pairs + (size_t)i * ROWCAP;
    for (int e = 0; e < cnt; ++e) {
        uint2 pk = pr[e];                  // wave-uniform broadcast load
        float d  = __uint_as_float(pk.y);
        unsigned j = pk.x;
        float sj = (float)seqTp[((size_t)(j >> 5) * 5 + (c >> 4)) * 512
                                + ((c & 15) + ((j >> 3) & 3) * 16) * 8 + (j & 7)];
        acc += d * sj;
        sdw += d;
    }
    float v = acc / (sb + sdw) + bias[c];
    out[(size_t)i * FOUT + c] = (v > 0.f) ? v : expm1f(v);
}

extern "C" void kernel_launch(void* const* d_in, const int* in_sizes, int n_in,
                              void* d_out, int out_size, void* d_ws, size_t ws_size,
                              hipStream_t stream) {
    const float* x    = (const float*)d_in[0];
    const float* rel  = (const float*)d_in[1];
    const float* adj  = (const float*)d_in[2];
    const int*   ep   = (const int*)d_in[3];
    const int*   rseg = (const int*)d_in[4];
    const float* W    = (const float*)d_in[5];
    const float* wrel = (const float*)d_in[6];
    const float* bias = (const float*)d_in[7];
    float* out = (float*)d_out;

    float* ws = (float*)d_ws;
    float*    sums   = ws + O_SUMS;
    float*    cnts   = ws + O_CNTS;
    int*      rowcnt = (int*)(ws + O_ROWCNT);
    unsigned* hkey   = (unsigned*)(ws + O_HKEY);
    unsigned* hprio  = (unsigned*)(ws + O_HPRIO);
    __bf16*   seqTp  = (__bf16*)(ws + O_SEQTP);
    float*    Nump   = ws + O_NUMP;
    float*    Sp     = ws + O_SP;
    uint2*    pairs  = (uint2*)(ws + O_PAIRS);

    int n4 = ZERO_WORDS / 4;
    k_zero<<<(n4 + 255) / 256, 256, 0, stream>>>((f32x4*)d_ws, n4);
    k_seqfts<<<NN / 16, 256, 0, stream>>>(x, W, seqTp);
    k_mr<<<GRID_MR, 512, 0, stream>>>(adj, seqTp, rel, wrel, rseg, ep,
                                      sums, cnts, hkey, hprio, Nump, Sp);
    k_scatB<<<(2 * EE + 255) / 256, 256, 0, stream>>>(ep, sums, cnts, hkey, hprio,
                                                      adj, rowcnt, pairs);
    k_rowupd<<<(NN + 3) / 4, 256, 0, stream>>>(Nump, Sp, rowcnt, pairs,
                                               seqTp, bias, out);
}